// Round 2
// baseline (62.881 us; speedup 1.0000x reference)
//
#include <hip/hip_runtime.h>
#include <math.h>

// NDFT type-2, separable 2D: B=2, M=8192, D=2, N=64x64 (K=4096).
// y[b,m] = sum_{k1,k2} f_hat[b,k1,k2] * exp(-2pi*i*((k1-32)*x1 + (k2-32)*x2))
// Factorized: inner k2 sweep via complex-rotation recurrence, outer k1 via sincosf.
//
// Output layout is runtime-detected via out_size:
//   out_size == 2*B*M -> planar: out[0:16384]=re(y), out[16384:32768]=im(y)
//   out_size ==   B*M -> real part only
// (Interleaved (re,im) pairs was tested in R1 and gave misalignment-signature
//  error 282.5 ~ sqrt(2)*max|y| -> ruled out.)

#define TWO_PI 6.28318530717958647692f
#define BM 16384   // B*M

__global__ __launch_bounds__(256) void ndft_kernel(
    const float* __restrict__ x,      // [B, M, 2]
    const float* __restrict__ f_hat,  // [B, 64, 64]
    float* __restrict__ out,
    int planar)                       // 1: split re/im halves, 0: real only
{
    __shared__ float fh[64 * 64];       // 16 KB: f_hat for this block's batch
    __shared__ float part[4][64][2];    // cross-wave partial sums

    const int t   = threadIdx.x;
    const int sub = t >> 6;   // wave id 0..3 -> k1 chunk (wave-uniform)
    const int lp  = t & 63;   // local point 0..63
    const int gp  = blockIdx.x * 64 + lp;   // global point in [0, 16384)
    const int b   = gp >> 13;               // / 8192  (64 | 8192 -> uniform per block)

    // Stage f_hat[b] (4096 floats) into LDS, float4-vectorized: 4 per thread.
    {
        const float4* src = (const float4*)(f_hat + b * 4096);
        float4* dst = (float4*)fh;
        #pragma unroll
        for (int i = 0; i < 4; ++i)
            dst[t + i * 256] = src[t + i * 256];
    }
    __syncthreads();

    // Coalesced point load.
    const float2 xp = ((const float2*)x)[gp];
    const float x1 = xp.x, x2 = xp.y;

    // k2 rotation step: e^{-2pi*i*x2} = c2 - i*s2
    float s2, c2;
    sincosf(TWO_PI * x2, &s2, &c2);
    // k2 start (k2=0 -> freq -32): e^{+2pi*i*32*x2}
    float w20i, w20r;
    sincosf(32.0f * TWO_PI * x2, &w20i, &w20r);

    float yr = 0.0f, yi = 0.0f;
    const int k1base = sub << 4;

    for (int k1i = 0; k1i < 16; ++k1i) {
        const int k1 = k1base + k1i;
        // w1 = e^{-2pi*i*(k1-32)*x1}
        float w1i_, w1r_;
        sincosf(-TWO_PI * (float)(k1 - 32) * x1, &w1i_, &w1r_);

        float wr = w20r, wi = w20i;     // w2 at k2=0
        float ir = 0.0f, ii = 0.0f;
        const float4* frow = (const float4*)(fh + (k1 << 6));  // wave-uniform: LDS broadcast
        #pragma unroll
        for (int q = 0; q < 16; ++q) {
            const float4 f = frow[q];
            {
                ir = fmaf(f.x, wr, ir); ii = fmaf(f.x, wi, ii);
                const float nr = fmaf(wr, c2,  wi * s2);
                const float ni = fmaf(wi, c2, -wr * s2);
                wr = nr; wi = ni;
            }
            {
                ir = fmaf(f.y, wr, ir); ii = fmaf(f.y, wi, ii);
                const float nr = fmaf(wr, c2,  wi * s2);
                const float ni = fmaf(wi, c2, -wr * s2);
                wr = nr; wi = ni;
            }
            {
                ir = fmaf(f.z, wr, ir); ii = fmaf(f.z, wi, ii);
                const float nr = fmaf(wr, c2,  wi * s2);
                const float ni = fmaf(wi, c2, -wr * s2);
                wr = nr; wi = ni;
            }
            {
                ir = fmaf(f.w, wr, ir); ii = fmaf(f.w, wi, ii);
                const float nr = fmaf(wr, c2,  wi * s2);
                const float ni = fmaf(wi, c2, -wr * s2);
                wr = nr; wi = ni;
            }
        }
        // y += w1 * inner  (complex multiply)
        yr = fmaf(w1r_, ir, fmaf(-w1i_, ii, yr));
        yi = fmaf(w1r_, ii, fmaf( w1i_, ir, yi));
    }

    part[sub][lp][0] = yr;
    part[sub][lp][1] = yi;
    __syncthreads();

    // Reduce 4 wave-partials per point; 128 threads handle 64 points x {re,im}.
    if (t < 128) {
        const int p = t >> 1, comp = t & 1;
        const float s = part[0][p][comp] + part[1][p][comp]
                      + part[2][p][comp] + part[3][p][comp];
        const int g = blockIdx.x * 64 + p;
        if (planar) {
            out[comp * BM + g] = s;        // [re plane | im plane]
        } else if (comp == 0) {
            out[g] = s;                    // real part only
        }
    }
}

extern "C" void kernel_launch(void* const* d_in, const int* in_sizes, int n_in,
                              void* d_out, int out_size, void* d_ws, size_t ws_size,
                              hipStream_t stream) {
    const float* x     = (const float*)d_in[0];   // [2, 8192, 2]
    const float* f_hat = (const float*)d_in[1];   // [2, 64, 64]
    float* out = (float*)d_out;

    const int planar = (out_size >= 2 * BM) ? 1 : 0;

    // 16384 points / 64 per block = 256 blocks
    ndft_kernel<<<dim3(256), dim3(256), 0, stream>>>(x, f_hat, out, planar);
}

// Round 3
// 62.156 us; speedup vs baseline: 1.0117x; 1.0117x over previous
//
#include <hip/hip_runtime.h>
#include <math.h>

// NDFT type-2, separable 2D: B=2, M=8192, D=2, N=64x64 (K=4096).
// y[b,m] = sum_{k1,k2} f_hat[b,k1,k2] * exp(-2pi*i*((k1-32)*x1 + (k2-32)*x2))
//
// Inner k2 sum via complex Horner: S = f[k2] + w2*S (4 VALU insts/step, w2 exact).
//   S_final = sum_k2 f[k2]*w2^k2,  w2 = e^{-2pi*i*x2}
// Outer k1: y += P*S, with P(k1) = e^{-2pi*i*(k1-32)*x1} * e^{+2pi*i*32*x2}
//   initialized by ONE combined-angle sincosf, stepped by rotation e^{-2pi*i*x1}.
// 3 sincosf total per thread.
//
// Output layout (R2-verified): planar — out[0:16384]=re(y), out[16384:32768]=im(y).
//
// Occupancy: 256 blocks x 512 threads = 2048 waves = 2 waves/SIMD (covers the
// 8-cyc Horner dependency chain; issue window is 16 cyc at 4 insts x 2 waves).

#define TWO_PI 6.28318530717958647692f
#define BM 16384   // B*M

__global__ __launch_bounds__(512) void ndft_kernel(
    const float* __restrict__ x,      // [B, M, 2]
    const float* __restrict__ f_hat,  // [B, 64, 64]
    float* __restrict__ out,
    int planar)
{
    __shared__ float fh[64 * 64];       // 16 KB: f_hat for this block's batch
    __shared__ float part[8][64][2];    // 4 KB: cross-wave partial sums

    const int t   = threadIdx.x;
    const int sub = t >> 6;   // wave id 0..7 -> k1 chunk of 8 (wave-uniform)
    const int lp  = t & 63;   // local point 0..63
    const int gp  = blockIdx.x * 64 + lp;   // global point in [0, 16384)
    const int b   = gp >> 13;               // 64 | 8192 -> uniform per block

    // Stage f_hat[b] (4096 floats = 1024 float4) into LDS: 2 per thread.
    {
        const float4* src = (const float4*)(f_hat + b * 4096);
        float4* dst = (float4*)fh;
        dst[t]       = src[t];
        dst[t + 512] = src[t + 512];
    }
    __syncthreads();

    const float2 xp = ((const float2*)x)[gp];
    const float x1 = xp.x, x2 = xp.y;

    // w2 = e^{-2pi*i*x2} = (c2, -s2)
    float s2, c2;
    sincosf(TWO_PI * x2, &s2, &c2);
    const float wr2 = c2, wi2 = -s2;

    // k1 rotation step e^{-2pi*i*x1}: multiplier (c1, -s1)
    float s1, c1;
    sincosf(TWO_PI * x1, &s1, &c1);

    const int k1base = sub << 3;
    // P init at k1 = k1base: angle = -2pi*(k1base-32)*x1 + 2pi*32*x2
    float Pr, Pi;
    {
        const float theta = fmaf(-TWO_PI * (float)(k1base - 32), x1,
                                 (32.0f * TWO_PI) * x2);
        sincosf(theta, &Pi, &Pr);
    }

    float yr = 0.0f, yi = 0.0f;

    for (int k1i = 0; k1i < 8; ++k1i) {
        const int k1 = k1base + k1i;
        const float4* frow = (const float4*)(fh + (k1 << 6));  // wave-uniform: broadcast

        // Horner over k2 = 63 .. 0:  S = f[k2] + w2*S
        float Sr = 0.0f, Si = 0.0f;
        #pragma unroll
        for (int q = 15; q >= 0; --q) {
            const float4 f = frow[q];
            {   // k2 = 4q+3
                const float nr = fmaf(wr2, Sr, fmaf(-wi2, Si, f.w));
                const float ni = fmaf(wr2, Si, wi2 * Sr);
                Sr = nr; Si = ni;
            }
            {   // k2 = 4q+2
                const float nr = fmaf(wr2, Sr, fmaf(-wi2, Si, f.z));
                const float ni = fmaf(wr2, Si, wi2 * Sr);
                Sr = nr; Si = ni;
            }
            {   // k2 = 4q+1
                const float nr = fmaf(wr2, Sr, fmaf(-wi2, Si, f.y));
                const float ni = fmaf(wr2, Si, wi2 * Sr);
                Sr = nr; Si = ni;
            }
            {   // k2 = 4q
                const float nr = fmaf(wr2, Sr, fmaf(-wi2, Si, f.x));
                const float ni = fmaf(wr2, Si, wi2 * Sr);
                Sr = nr; Si = ni;
            }
        }

        // y += P * S   (complex)
        yr = fmaf(Pr, Sr, fmaf(-Pi, Si, yr));
        yi = fmaf(Pr, Si, fmaf( Pi, Sr, yi));

        // P *= e^{-2pi*i*x1} = (c1, -s1)
        const float nPr = fmaf(Pr, c1,  Pi * s1);
        const float nPi = fmaf(Pi, c1, -Pr * s1);
        Pr = nPr; Pi = nPi;
    }

    part[sub][lp][0] = yr;
    part[sub][lp][1] = yi;
    __syncthreads();

    // Reduce 8 wave-partials; threads 0..127 cover 64 points x {re,im}.
    if (t < 128) {
        const int p = t >> 1, comp = t & 1;
        float s = 0.0f;
        #pragma unroll
        for (int w = 0; w < 8; ++w) s += part[w][p][comp];
        const int g = blockIdx.x * 64 + p;
        if (planar) {
            out[comp * BM + g] = s;        // [re plane | im plane]
        } else if (comp == 0) {
            out[g] = s;
        }
    }
}

extern "C" void kernel_launch(void* const* d_in, const int* in_sizes, int n_in,
                              void* d_out, int out_size, void* d_ws, size_t ws_size,
                              hipStream_t stream) {
    const float* x     = (const float*)d_in[0];   // [2, 8192, 2]
    const float* f_hat = (const float*)d_in[1];   // [2, 64, 64]
    float* out = (float*)d_out;

    const int planar = (out_size >= 2 * BM) ? 1 : 0;

    ndft_kernel<<<dim3(256), dim3(512), 0, stream>>>(x, f_hat, out, planar);
}